// Round 1
// baseline (161.703 us; speedup 1.0000x reference)
//
#include <hip/hip_runtime.h>
#include <math.h>

#define B_     16
#define NX_    8192
#define C_     128
#define K1_    17          // kx + 1 retained frequencies
#define NC_    32          // n-chunks for forward kernel
#define SLOTS_ (NC_ * 2)   // partial-sum slots (2 halves per chunk)

// Workspace layout (floats):
//   trigT : [NX][K1] float2 (cos, sin)                 NX*K1*2 floats (1.1 MB)
//   Gpart : [B][SLOTS][K1][2(r,i)][C] floats           (17.8 MB)
//   Acoef : [B][K1][C] float2 (ar, ai)                 (0.28 MB)
#define TRIG_F  (NX_ * K1_ * 2)
#define GPART_F ((size_t)B_ * SLOTS_ * K1_ * 2 * C_)
#define ACOEF_F ((size_t)B_ * K1_ * C_ * 2)

__global__ __launch_bounds__(256) void k_trig(float* __restrict__ ws) {
    int idx = blockIdx.x * 256 + threadIdx.x;   // idx = n*K1 + k
    if (idx >= NX_ * K1_) return;
    int n = idx / K1_;
    int k = idx - n * K1_;
    int m = (k * n) & (NX_ - 1);                // (k*n) mod NX, keeps angle in [0, 2pi)
    float th = (float)m * (6.283185307179586f / (float)NX_);
    float s, c;
    sincosf(th, &s, &c);
    ws[2 * idx]     = c;
    ws[2 * idx + 1] = s;
}

// Forward truncated DFT: partial sums over an n-range per block-half.
__global__ __launch_bounds__(256) void k_fwd(const float* __restrict__ x,
                                             float* __restrict__ ws) {
    const float2* trig = (const float2*)ws;
    float* gpart = ws + TRIG_F;

    const int b = blockIdx.y;
    const int chunk = blockIdx.x;
    const int t = threadIdx.x;
    const int j = t & (C_ - 1);     // column
    const int h = t >> 7;           // which half of the chunk's n-range
    const int nspan = NX_ / NC_ / 2;        // 128
    const int n0 = chunk * (NX_ / NC_) + h * nspan;

    float gr[K1_], gi[K1_];
#pragma unroll
    for (int k = 0; k < K1_; ++k) { gr[k] = 0.f; gi[k] = 0.f; }

    const float* xp = x + ((size_t)b * NX_ + n0) * C_ + j;
    for (int nn = 0; nn < nspan; ++nn) {
        float xv = xp[(size_t)nn * C_];                 // coalesced across lanes
        const float2* tr = trig + (size_t)(n0 + nn) * K1_;  // wave-uniform row
#pragma unroll
        for (int k = 0; k < K1_; ++k) {
            float2 cs = tr[k];
            gr[k] = fmaf(xv,  cs.x, gr[k]);   // sum x*cos
            gi[k] = fmaf(xv, -cs.y, gi[k]);   // -sum x*sin
        }
    }

    const int slot = chunk * 2 + h;
    float* gp = gpart + (((size_t)b * SLOTS_ + slot) * K1_) * 2 * C_;
#pragma unroll
    for (int k = 0; k < K1_; ++k) {
        gp[(k * 2 + 0) * C_ + j] = gr[k];
        gp[(k * 2 + 1) * C_ + j] = gi[k];
    }
}

// Reduce partials, apply complex weight matmul, fold irfft scaling into coefs.
__global__ __launch_bounds__(128) void k_mix(const float* __restrict__ wr_g,
                                             const float* __restrict__ wi_g,
                                             float* __restrict__ ws) {
    const int k = blockIdx.x;
    const int b = blockIdx.y;
    const int i = threadIdx.x;

    const float* gpart = ws + TRIG_F;
    float2* acoef = (float2*)(ws + TRIG_F + GPART_F);

    __shared__ float grs[C_], gis[C_];

    float gr = 0.f, gi = 0.f;
    for (int s = 0; s < SLOTS_; ++s) {
        const float* gp = gpart + (((size_t)b * SLOTS_ + s) * K1_ + k) * 2 * C_;
        gr += gp[i];
        gi += gp[C_ + i];
    }
    grs[i] = gr;
    gis[i] = gi;
    __syncthreads();

    float hr = 0.f, hi = 0.f;
    const float* wrp = wr_g + ((size_t)k * C_ + i) * C_;
    const float* wip = wi_g + ((size_t)k * C_ + i) * C_;
    for (int jj = 0; jj < C_; ++jj) {
        float wr = wrp[jj], wi = wip[jj];
        float a = grs[jj], c = gis[jj];
        hr = fmaf(wr, a, hr); hr = fmaf(-wi, c, hr);   // Re(W*G)
        hi = fmaf(wr, c, hi); hi = fmaf( wi, a, hi);   // Im(W*G)
    }

    // out[n] = sum_k c_k*(hr*cos - hi*sin)  ->  ar = c*hr, ai = -c*hi
    float cf = (k == 0 ? 1.0f : 2.0f) / (float)NX_;
    acoef[((size_t)b * K1_ + k) * C_ + i] = make_float2(cf * hr, -cf * hi);
}

// Inverse: out[b,n,i] = sum_k ar[k,i]*cos(th_kn) + ai[k,i]*sin(th_kn)
__global__ __launch_bounds__(256) void k_inv(float* __restrict__ out,
                                             const float* __restrict__ ws) {
    const float2* trig = (const float2*)ws;
    const float4* acoef4 = (const float4*)(ws + TRIG_F + GPART_F);

    const int b = blockIdx.y;
    const int t = threadIdx.x;
    const int jp = t & 63;          // column pair: 2*jp, 2*jp+1
    const int h = t >> 6;           // n sub-range within block
    const int n0 = blockIdx.x * 256 + h * 64;

    float ar0[K1_], ai0[K1_], ar1[K1_], ai1[K1_];
#pragma unroll
    for (int k = 0; k < K1_; ++k) {
        float4 a = acoef4[((size_t)b * K1_ + k) * (C_ / 2) + jp];
        ar0[k] = a.x; ai0[k] = a.y; ar1[k] = a.z; ai1[k] = a.w;
    }

    for (int nn = 0; nn < 64; ++nn) {
        const int n = n0 + nn;
        const float2* tr = trig + (size_t)n * K1_;   // wave-uniform row
        float o0 = 0.f, o1 = 0.f;
#pragma unroll
        for (int k = 0; k < K1_; ++k) {
            float2 cs = tr[k];
            o0 = fmaf(ar0[k], cs.x, o0); o0 = fmaf(ai0[k], cs.y, o0);
            o1 = fmaf(ar1[k], cs.x, o1); o1 = fmaf(ai1[k], cs.y, o1);
        }
        ((float2*)(out + ((size_t)b * NX_ + n) * C_))[jp] = make_float2(o0, o1);
    }
}

extern "C" void kernel_launch(void* const* d_in, const int* in_sizes, int n_in,
                              void* d_out, int out_size, void* d_ws, size_t ws_size,
                              hipStream_t stream) {
    const float* x  = (const float*)d_in[0];   // (B, NX, C) fp32
    const float* wr = (const float*)d_in[1];   // (K1, C, C) fp32
    const float* wi = (const float*)d_in[2];   // (K1, C, C) fp32
    float* out = (float*)d_out;                // (B, NX, C) fp32
    float* ws  = (float*)d_ws;                 // needs ~19.2 MB

    k_trig<<<(NX_ * K1_ + 255) / 256, 256, 0, stream>>>(ws);
    k_fwd<<<dim3(NC_, B_), 256, 0, stream>>>(x, ws);
    k_mix<<<dim3(K1_, B_), 128, 0, stream>>>(wr, wi, ws);
    k_inv<<<dim3(NX_ / 256, B_), 256, 0, stream>>>(out, ws);
}

// Round 2
// 78.632 us; speedup vs baseline: 2.0565x; 2.0565x over previous
//
#include <hip/hip_runtime.h>
#include <math.h>

#define B_     16
#define NX_    8192
#define C_     128
#define K1_    17          // kx + 1 retained frequencies
#define NC_    64          // n-chunks for forward kernel (1 slot each)
#define NSP_   128         // n-span per chunk/block

// Workspace layout (floats):
//   trigT : [NX][K1] float2 (cos, sin)            NX*K1*2 floats (1.11 MB)
//   Gpart : [B][NC][K1][2(r,i)][C] floats         (17.8 MB)
//   Acoef : [B][K1][C] float2 (ar, ai)            (0.28 MB)
#define TRIG_F  (NX_ * K1_ * 2)
#define GPART_F ((size_t)B_ * NC_ * K1_ * 2 * C_)

__global__ __launch_bounds__(256) void k_trig(float* __restrict__ ws) {
    int idx = blockIdx.x * 256 + threadIdx.x;   // idx = n*K1 + k
    if (idx >= NX_ * K1_) return;
    int n = idx / K1_;
    int k = idx - n * K1_;
    int m = (k * n) & (NX_ - 1);                // (k*n) mod NX -> angle in [0, 2pi)
    float th = (float)m * (6.283185307179586f / (float)NX_);
    float s, c;
    sincosf(th, &s, &c);
    ws[2 * idx]     = c;
    ws[2 * idx + 1] = s;
}

// Forward truncated DFT. Block = (b, chunk of 128 n). Trig staged in LDS.
// Lane owns 2 channels; 4 h-groups of 32 n each, reduced in LDS to 1 slot.
__global__ __launch_bounds__(256) void k_fwd(const float* __restrict__ x,
                                             float* __restrict__ ws) {
    __shared__ float smem[2 * 64 * 69];         // 8832 floats; trig uses first 4352

    float* gpart = ws + TRIG_F;
    const int b = blockIdx.y;
    const int chunk = blockIdx.x;
    const int t = threadIdx.x;
    const int j2 = t & 63;          // channel pair: 2*j2, 2*j2+1
    const int h = t >> 6;           // n-subrange (one per wave)
    const int n0 = chunk * NSP_;

    // stage 128 trig rows (128*34 floats) into LDS, coalesced
    {
        const float* tg = ws + (size_t)n0 * (K1_ * 2);
        for (int idx = t; idx < NSP_ * K1_ * 2; idx += 256) smem[idx] = tg[idx];
    }
    __syncthreads();

    float2 gr[K1_], gi[K1_];
#pragma unroll
    for (int k = 0; k < K1_; ++k) {
        gr[k] = make_float2(0.f, 0.f);
        gi[k] = make_float2(0.f, 0.f);
    }

    const float2* xp = (const float2*)(x + ((size_t)b * NX_ + n0 + h * 32) * C_) + j2;
    const float2* tl = (const float2*)smem + (size_t)h * 32 * K1_;
#pragma unroll 4
    for (int nn = 0; nn < 32; ++nn) {
        float2 xv = xp[(size_t)nn * (C_ / 2)];          // coalesced 512B/wave
        const float2* tr = tl + nn * K1_;               // wave-uniform LDS row
#pragma unroll
        for (int k = 0; k < K1_; ++k) {
            float2 cs = tr[k];
            gr[k].x = fmaf(xv.x,  cs.x, gr[k].x);
            gr[k].y = fmaf(xv.y,  cs.x, gr[k].y);
            gi[k].x = fmaf(xv.x, -cs.y, gi[k].x);
            gi[k].y = fmaf(xv.y, -cs.y, gi[k].y);
        }
    }

    // two-round reduction across h-groups (reuses trig LDS space)
    __syncthreads();
    if (h >= 2) {
        float* p = smem + ((h - 2) * 64 + j2) * 69;
#pragma unroll
        for (int k = 0; k < K1_; ++k) {
            p[4 * k + 0] = gr[k].x; p[4 * k + 1] = gr[k].y;
            p[4 * k + 2] = gi[k].x; p[4 * k + 3] = gi[k].y;
        }
    }
    __syncthreads();
    if (h < 2) {
        const float* p = smem + (h * 64 + j2) * 69;
#pragma unroll
        for (int k = 0; k < K1_; ++k) {
            gr[k].x += p[4 * k + 0]; gr[k].y += p[4 * k + 1];
            gi[k].x += p[4 * k + 2]; gi[k].y += p[4 * k + 3];
        }
    }
    __syncthreads();
    if (h == 1) {
        float* p = smem + j2 * 69;
#pragma unroll
        for (int k = 0; k < K1_; ++k) {
            p[4 * k + 0] = gr[k].x; p[4 * k + 1] = gr[k].y;
            p[4 * k + 2] = gi[k].x; p[4 * k + 3] = gi[k].y;
        }
    }
    __syncthreads();
    if (h == 0) {
        const float* p = smem + j2 * 69;
#pragma unroll
        for (int k = 0; k < K1_; ++k) {
            gr[k].x += p[4 * k + 0]; gr[k].y += p[4 * k + 1];
            gi[k].x += p[4 * k + 2]; gi[k].y += p[4 * k + 3];
        }
        float* gp = gpart + (((size_t)b * NC_ + chunk) * K1_) * 2 * C_;
#pragma unroll
        for (int k = 0; k < K1_; ++k) {
            ((float2*)(gp + (k * 2 + 0) * C_))[j2] = gr[k];
            ((float2*)(gp + (k * 2 + 1) * C_))[j2] = gi[k];
        }
    }
}

// Reduce NC slots, apply complex weight matmul, fold irfft scaling into coefs.
__global__ __launch_bounds__(128) void k_mix(const float* __restrict__ wr_g,
                                             const float* __restrict__ wi_g,
                                             float* __restrict__ ws) {
    const int k = blockIdx.x;
    const int b = blockIdx.y;
    const int i = threadIdx.x;

    const float* gpart = ws + TRIG_F;
    float2* acoef = (float2*)(ws + TRIG_F + GPART_F);

    __shared__ float grs[C_], gis[C_];

    float gr = 0.f, gi = 0.f;
    for (int s = 0; s < NC_; ++s) {
        const float* gp = gpart + (((size_t)b * NC_ + s) * K1_ + k) * 2 * C_;
        gr += gp[i];
        gi += gp[C_ + i];
    }
    grs[i] = gr;
    gis[i] = gi;
    __syncthreads();

    float hr = 0.f, hi = 0.f;
    const float* wrp = wr_g + ((size_t)k * C_ + i) * C_;
    const float* wip = wi_g + ((size_t)k * C_ + i) * C_;
    for (int jj = 0; jj < C_; ++jj) {
        float wr = wrp[jj], wi = wip[jj];
        float a = grs[jj], c = gis[jj];
        hr = fmaf(wr, a, hr); hr = fmaf(-wi, c, hr);   // Re(W*G)
        hi = fmaf(wr, c, hi); hi = fmaf( wi, a, hi);   // Im(W*G)
    }

    // out[n] = sum_k c_k*(hr*cos - hi*sin)  ->  ar = c*hr, ai = -c*hi
    float cf = (k == 0 ? 1.0f : 2.0f) / (float)NX_;
    acoef[((size_t)b * K1_ + k) * C_ + i] = make_float2(cf * hr, -cf * hi);
}

// Inverse: out[b,n,i] = sum_k ar[k,i]*cos(th_kn) + ai[k,i]*sin(th_kn)
// Block = (b, 128 n). Trig staged in LDS.
__global__ __launch_bounds__(256) void k_inv(float* __restrict__ out,
                                             const float* __restrict__ ws) {
    __shared__ float smem[NSP_ * K1_ * 2];      // 4352 floats

    const float4* acoef4 = (const float4*)(ws + TRIG_F + GPART_F);
    const int b = blockIdx.y;
    const int t = threadIdx.x;
    const int jp = t & 63;          // channel pair: 2*jp, 2*jp+1
    const int h = t >> 6;           // n-subrange (one per wave)
    const int n0 = blockIdx.x * NSP_;

    {
        const float* tg = ws + (size_t)n0 * (K1_ * 2);
        for (int idx = t; idx < NSP_ * K1_ * 2; idx += 256) smem[idx] = tg[idx];
    }

    float ar0[K1_], ai0[K1_], ar1[K1_], ai1[K1_];
#pragma unroll
    for (int k = 0; k < K1_; ++k) {
        float4 a = acoef4[((size_t)b * K1_ + k) * (C_ / 2) + jp];
        ar0[k] = a.x; ai0[k] = a.y; ar1[k] = a.z; ai1[k] = a.w;
    }
    __syncthreads();

    const float2* tl = (const float2*)smem + (size_t)h * 32 * K1_;
    float* op = out + ((size_t)b * NX_ + n0 + h * 32) * C_;
#pragma unroll 4
    for (int nn = 0; nn < 32; ++nn) {
        const float2* tr = tl + nn * K1_;               // wave-uniform LDS row
        float o0 = 0.f, o1 = 0.f;
#pragma unroll
        for (int k = 0; k < K1_; ++k) {
            float2 cs = tr[k];
            o0 = fmaf(ar0[k], cs.x, o0); o0 = fmaf(ai0[k], cs.y, o0);
            o1 = fmaf(ar1[k], cs.x, o1); o1 = fmaf(ai1[k], cs.y, o1);
        }
        ((float2*)(op + (size_t)nn * C_))[jp] = make_float2(o0, o1);
    }
}

extern "C" void kernel_launch(void* const* d_in, const int* in_sizes, int n_in,
                              void* d_out, int out_size, void* d_ws, size_t ws_size,
                              hipStream_t stream) {
    const float* x  = (const float*)d_in[0];   // (B, NX, C) fp32
    const float* wr = (const float*)d_in[1];   // (K1, C, C) fp32
    const float* wi = (const float*)d_in[2];   // (K1, C, C) fp32
    float* out = (float*)d_out;                // (B, NX, C) fp32
    float* ws  = (float*)d_ws;                 // ~19.2 MB used

    k_trig<<<(NX_ * K1_ + 255) / 256, 256, 0, stream>>>(ws);
    k_fwd<<<dim3(NC_, B_), 256, 0, stream>>>(x, ws);
    k_mix<<<dim3(K1_, B_), 128, 0, stream>>>(wr, wi, ws);
    k_inv<<<dim3(NX_ / NSP_, B_), 256, 0, stream>>>(out, ws);
}

// Round 3
// 68.067 us; speedup vs baseline: 2.3756x; 1.1552x over previous
//
#include <hip/hip_runtime.h>
#include <math.h>

#define B_     16
#define NX_    8192
#define C_     128
#define K1_    17          // kx + 1 retained frequencies
#define NC_    64          // n-chunks for forward kernel (1 slot each)
#define NSP_   128         // n-span per chunk/block

typedef float v2f __attribute__((ext_vector_type(2)));

// Workspace layout (floats):
//   Gpart : [B][NC][K1][2(re-sum, sin-sum)][C]    (17.8 MB)
//   Acoef : [B][K1][C] float2 (ar, ai)            (0.28 MB)
#define GPART_F ((size_t)B_ * NC_ * K1_ * 2 * C_)

// ---------------------------------------------------------------------------
// Forward truncated DFT. Block = (b, chunk of 128 n).
// Trig computed in-block into LDS, duplicated {c,c}/{s,s} for packed FMA.
// Accumulates gr = sum x*cos, gs = sum x*sin  (G = gr - i*gs).
// ---------------------------------------------------------------------------
__global__ __launch_bounds__(256) void k_fwd(const float* __restrict__ x,
                                             float* __restrict__ ws) {
    __shared__ float smem[8960];        // trig: 8704 floats; reduction: 8960

    float* gpart = ws;
    const int b = blockIdx.y;
    const int chunk = blockIdx.x;
    const int t = threadIdx.x;
    const int j2 = t & 63;              // channel pair 2*j2, 2*j2+1
    const int h = t >> 6;               // n-subrange (one per wave)
    const int n0 = chunk * NSP_;

    // build duplicated trig table: row n -> 17 x {c,c} then 17 x {s,s}
    {
        float2* s2 = (float2*)smem;
        for (int idx = t; idx < NSP_ * K1_; idx += 256) {
            int nn = idx / K1_;
            int k = idx - nn * K1_;
            int m = (k * (n0 + nn)) & (NX_ - 1);
            float rev = (float)m * (1.0f / (float)NX_);   // exact
            float c = __builtin_amdgcn_cosf(rev);          // cos(2*pi*rev)
            float s = __builtin_amdgcn_sinf(rev);          // sin(2*pi*rev)
            s2[nn * 34 + k]      = make_float2(c, c);
            s2[nn * 34 + 17 + k] = make_float2(s, s);
        }
    }
    __syncthreads();

    v2f gr[K1_], gs[K1_];
#pragma unroll
    for (int k = 0; k < K1_; ++k) { gr[k] = (v2f)(0.f); gs[k] = (v2f)(0.f); }

    const v2f* xp = (const v2f*)(x + ((size_t)b * NX_ + n0 + h * 32) * C_) + j2;
    const v2f* tl = (const v2f*)smem + (size_t)h * 32 * 34;
#pragma unroll 2
    for (int nn = 0; nn < 32; ++nn) {
        v2f xv = xp[(size_t)nn * 64];                   // coalesced 512B/wave
        const v2f* tr = tl + nn * 34;                   // wave-uniform LDS row
#pragma unroll
        for (int k = 0; k < K1_; ++k) {
            gr[k] = __builtin_elementwise_fma(xv, tr[k],      gr[k]);
            gs[k] = __builtin_elementwise_fma(xv, tr[17 + k], gs[k]);
        }
    }

    // two-round reduction across h-groups (reuses trig LDS space)
    // rows of 35 float2 (stride 70 floats, 2-way banks = free)
    float2* red = (float2*)smem;
    __syncthreads();
    if (h >= 2) {
        float2* p = red + ((h - 2) * 64 + j2) * 35;
#pragma unroll
        for (int k = 0; k < K1_; ++k) {
            p[2 * k]     = make_float2(gr[k].x, gr[k].y);
            p[2 * k + 1] = make_float2(gs[k].x, gs[k].y);
        }
    }
    __syncthreads();
    if (h < 2) {
        const float2* p = red + (h * 64 + j2) * 35;
#pragma unroll
        for (int k = 0; k < K1_; ++k) {
            float2 a = p[2 * k], c = p[2 * k + 1];
            gr[k].x += a.x; gr[k].y += a.y;
            gs[k].x += c.x; gs[k].y += c.y;
        }
    }
    __syncthreads();
    if (h == 1) {
        float2* p = red + j2 * 35;
#pragma unroll
        for (int k = 0; k < K1_; ++k) {
            p[2 * k]     = make_float2(gr[k].x, gr[k].y);
            p[2 * k + 1] = make_float2(gs[k].x, gs[k].y);
        }
    }
    __syncthreads();
    if (h == 0) {
        const float2* p = red + j2 * 35;
        float* gp = gpart + (((size_t)b * NC_ + chunk) * K1_) * 2 * C_;
#pragma unroll
        for (int k = 0; k < K1_; ++k) {
            float2 a = p[2 * k], c = p[2 * k + 1];
            gr[k].x += a.x; gr[k].y += a.y;
            gs[k].x += c.x; gs[k].y += c.y;
            ((v2f*)(gp + (k * 2 + 0) * C_))[j2] = gr[k];
            ((v2f*)(gp + (k * 2 + 1) * C_))[j2] = gs[k];
        }
    }
}

// ---------------------------------------------------------------------------
// Reduce NC slots, apply complex weight matmul (sign-folded for gs = +sum x*s),
// fold irfft scaling into coefs. 256 threads: slots and jj both split in two.
// ---------------------------------------------------------------------------
__global__ __launch_bounds__(256) void k_mix(const float* __restrict__ wr_g,
                                             const float* __restrict__ wi_g,
                                             float* __restrict__ ws) {
    const int k = blockIdx.x;
    const int b = blockIdx.y;
    const int t = threadIdx.x;
    const int i = t & 127;
    const int h = t >> 7;

    const float* gpart = ws;
    float2* acoef = (float2*)(ws + GPART_F);

    __shared__ float grs[C_], gss[C_], tr_[C_], ti_[C_];

    float gr = 0.f, gs = 0.f;
    const float* base = gpart + ((size_t)b * NC_) * K1_ * 2 * C_ + (size_t)k * 2 * C_;
    for (int s = h * 32; s < h * 32 + 32; ++s) {
        const float* gp = base + (size_t)s * (K1_ * 2 * C_);
        gr += gp[i];
        gs += gp[C_ + i];
    }
    if (h) { tr_[i] = gr; ti_[i] = gs; }
    __syncthreads();
    if (!h) { grs[i] = gr + tr_[i]; gss[i] = gs + ti_[i]; }
    __syncthreads();

    // H = W * (gr - i*gs):  hr = wr*gr + wi*gs ; hi = wi*gr - wr*gs
    float hr = 0.f, hi = 0.f;
    const float* wrp = wr_g + ((size_t)k * C_ + i) * C_;
    const float* wip = wi_g + ((size_t)k * C_ + i) * C_;
    for (int jj = h * 64; jj < h * 64 + 64; ++jj) {
        float wr = wrp[jj], wi = wip[jj];
        float a = grs[jj], c = gss[jj];
        hr = fmaf(wr, a, hr); hr = fmaf( wi, c, hr);
        hi = fmaf(wi, a, hi); hi = fmaf(-wr, c, hi);
    }
    __syncthreads();
    if (h) { tr_[i] = hr; ti_[i] = hi; }
    __syncthreads();
    if (!h) {
        hr += tr_[i]; hi += ti_[i];
        // out[n] = sum_k c_k*(hr*cos - hi*sin) -> ar = c*hr, ai = -c*hi
        float cf = (k == 0 ? 1.0f : 2.0f) / (float)NX_;
        acoef[((size_t)b * K1_ + k) * C_ + i] = make_float2(cf * hr, -cf * hi);
    }
}

// ---------------------------------------------------------------------------
// Inverse: out[b,n,i] = sum_k ar[k,i]*cos + ai[k,i]*sin. Trig in LDS (packed).
// ---------------------------------------------------------------------------
__global__ __launch_bounds__(256) void k_inv(float* __restrict__ out,
                                             const float* __restrict__ ws) {
    __shared__ float smem[8704];

    const float4* acoef4 = (const float4*)(ws + GPART_F);
    const int b = blockIdx.y;
    const int t = threadIdx.x;
    const int jp = t & 63;          // channel pair 2*jp, 2*jp+1
    const int h = t >> 6;           // n-subrange (one per wave)
    const int n0 = blockIdx.x * NSP_;

    {
        float2* s2 = (float2*)smem;
        for (int idx = t; idx < NSP_ * K1_; idx += 256) {
            int nn = idx / K1_;
            int k = idx - nn * K1_;
            int m = (k * (n0 + nn)) & (NX_ - 1);
            float rev = (float)m * (1.0f / (float)NX_);
            float c = __builtin_amdgcn_cosf(rev);
            float s = __builtin_amdgcn_sinf(rev);
            s2[nn * 34 + k]      = make_float2(c, c);
            s2[nn * 34 + 17 + k] = make_float2(s, s);
        }
    }

    v2f arP[K1_], aiP[K1_];
#pragma unroll
    for (int k = 0; k < K1_; ++k) {
        float4 a = acoef4[((size_t)b * K1_ + k) * (C_ / 2) + jp];
        arP[k] = (v2f){a.x, a.z};
        aiP[k] = (v2f){a.y, a.w};
    }
    __syncthreads();

    const v2f* tl = (const v2f*)smem + (size_t)h * 32 * 34;
    float* op = out + ((size_t)b * NX_ + n0 + h * 32) * C_;
#pragma unroll 2
    for (int nn = 0; nn < 32; ++nn) {
        const v2f* tr = tl + nn * 34;
        v2f o = (v2f)(0.f);
#pragma unroll
        for (int k = 0; k < K1_; ++k) {
            o = __builtin_elementwise_fma(arP[k], tr[k],      o);
            o = __builtin_elementwise_fma(aiP[k], tr[17 + k], o);
        }
        ((v2f*)(op + (size_t)nn * C_))[jp] = o;
    }
}

extern "C" void kernel_launch(void* const* d_in, const int* in_sizes, int n_in,
                              void* d_out, int out_size, void* d_ws, size_t ws_size,
                              hipStream_t stream) {
    const float* x  = (const float*)d_in[0];   // (B, NX, C) fp32
    const float* wr = (const float*)d_in[1];   // (K1, C, C) fp32
    const float* wi = (const float*)d_in[2];   // (K1, C, C) fp32
    float* out = (float*)d_out;                // (B, NX, C) fp32
    float* ws  = (float*)d_ws;                 // ~18.1 MB used

    k_fwd<<<dim3(NC_, B_), 256, 0, stream>>>(x, ws);
    k_mix<<<dim3(K1_, B_), 256, 0, stream>>>(wr, wi, ws);
    k_inv<<<dim3(NX_ / NSP_, B_), 256, 0, stream>>>(out, ws);
}